// Round 5
// baseline (99.664 us; speedup 1.0000x reference)
//
#include <hip/hip_runtime.h>

#define FEAT 64
#define HALF 32

typedef float vfloat4 __attribute__((ext_vector_type(4)));

static __device__ __forceinline__ unsigned short f2bf(float f) {
    unsigned u = __float_as_uint(f);
    unsigned r = (u + 0x7FFF + ((u >> 16) & 1)) >> 16;   // RNE
    return (unsigned short)r;
}
static __device__ __forceinline__ float bf_lo(unsigned u) { return __uint_as_float(u << 16); }
static __device__ __forceinline__ float bf_hi(unsigned u) { return __uint_as_float(u & 0xffff0000u); }

// Fused prep: features -> bf16 split-half tables, plus CSR row_start via
// binary search on sorted edge_dst.
__global__ void prep(const float* __restrict__ feat,
                     const int* __restrict__ edge_dst,
                     unsigned short* __restrict__ fbh,   // [2][N][32]
                     int* __restrict__ row_start, int N, int E) {
    int t = blockIdx.x * blockDim.x + threadIdx.x;
    int total = N * 8;                      // N × 2 halves × 4 chunks(8 bf16)
    if (t < total) {
        int n = t >> 3, h = (t >> 2) & 1, q = t & 3;
        const float* src = feat + (size_t)n * FEAT + h * HALF + q * 8;
        float4 a = *(const float4*)src;
        float4 b = *(const float4*)(src + 4);
        uint4 o;
        o.x = (unsigned)f2bf(a.x) | ((unsigned)f2bf(a.y) << 16);
        o.y = (unsigned)f2bf(a.z) | ((unsigned)f2bf(a.w) << 16);
        o.z = (unsigned)f2bf(b.x) | ((unsigned)f2bf(b.y) << 16);
        o.w = (unsigned)f2bf(b.z) | ((unsigned)f2bf(b.w) << 16);
        *(uint4*)(fbh + (size_t)h * N * HALF + (size_t)n * HALF + q * 8) = o;
    }
    if (t <= N) {
        int lo = 0, hi = E;
        while (lo < hi) { int mid = (lo + hi) >> 1; if (edge_dst[mid] < t) lo = mid + 1; else hi = mid; }
        row_start[t] = lo;
    }
}

// One wave per node, half-row gather: eg = lane>>2 (16 edges in flight),
// fq = lane&3 (16B chunk of the 64B half-row).
template<int H>
__global__ void __launch_bounds__(256) hop1_half(
        const float* __restrict__ feat,
        const unsigned short* __restrict__ fbh_h,   // half-H table [N][32]
        const int* __restrict__ edge_src,
        const int* __restrict__ row_start,
        float* __restrict__ out,
        unsigned short* __restrict__ agg1h_h,       // half-H agg1 [N][32]
        int N) {
    int wave = (blockIdx.x * blockDim.x + threadIdx.x) >> 6;
    if (wave >= N) return;
    int lane = threadIdx.x & 63;
    int eg = lane >> 2;
    int fq = lane & 3;
    int s = row_start[wave];
    int e = row_start[wave + 1];

    float acc[8] = {0.f,0.f,0.f,0.f,0.f,0.f,0.f,0.f};
    for (int i = s + eg; i < e; i += 16) {
        int src = edge_src[i];
        uint4 p = *(const uint4*)(fbh_h + (size_t)src * HALF + fq * 8);
        acc[0] += bf_lo(p.x); acc[1] += bf_hi(p.x);
        acc[2] += bf_lo(p.y); acc[3] += bf_hi(p.y);
        acc[4] += bf_lo(p.z); acc[5] += bf_hi(p.z);
        acc[6] += bf_lo(p.w); acc[7] += bf_hi(p.w);
    }
    #pragma unroll
    for (int m = 4; m <= 32; m <<= 1) {
        #pragma unroll
        for (int k = 0; k < 8; ++k) acc[k] += __shfl_xor(acc[k], m, 64);
    }
    float inv = 1.0f / (float)((e - s) > 0 ? (e - s) : 1);
    #pragma unroll
    for (int k = 0; k < 8; ++k) acc[k] *= inv;

    float* orow = out + (size_t)wave * 256;
    vfloat4 v0 = {acc[0], acc[1], acc[2], acc[3]};
    vfloat4 v1 = {acc[4], acc[5], acc[6], acc[7]};
    if (eg == 0) {            // cols 64+32H.. : agg1 f32
        __builtin_nontemporal_store(v0, (vfloat4*)(orow + 64 + H * HALF + fq * 8));
        __builtin_nontemporal_store(v1, (vfloat4*)(orow + 64 + H * HALF + fq * 8 + 4));
    } else if (eg == 1) {     // cols 128+32H.. : agg1 dup (== agg2[:,0:64] half)
        __builtin_nontemporal_store(v0, (vfloat4*)(orow + 128 + H * HALF + fq * 8));
        __builtin_nontemporal_store(v1, (vfloat4*)(orow + 128 + H * HALF + fq * 8 + 4));
    } else if (eg == 2) {     // agg1 bf16 half -> ws (hop2's gather table)
        uint4 pk;
        pk.x = (unsigned)f2bf(acc[0]) | ((unsigned)f2bf(acc[1]) << 16);
        pk.y = (unsigned)f2bf(acc[2]) | ((unsigned)f2bf(acc[3]) << 16);
        pk.z = (unsigned)f2bf(acc[4]) | ((unsigned)f2bf(acc[5]) << 16);
        pk.w = (unsigned)f2bf(acc[6]) | ((unsigned)f2bf(acc[7]) << 16);
        *(uint4*)(agg1h_h + (size_t)wave * HALF + fq * 8) = pk;
    } else if (eg == 3) {     // cols 32H.. : features f32 copy (half)
        const float* frow = feat + (size_t)wave * FEAT + H * HALF + fq * 8;
        vfloat4 f0 = __builtin_nontemporal_load((const vfloat4*)frow);
        vfloat4 f1 = __builtin_nontemporal_load((const vfloat4*)(frow + 4));
        __builtin_nontemporal_store(f0, (vfloat4*)(orow + H * HALF + fq * 8));
        __builtin_nontemporal_store(f1, (vfloat4*)(orow + H * HALF + fq * 8 + 4));
    }
}

template<int H>
__global__ void __launch_bounds__(256) hop2_half(
        const unsigned short* __restrict__ agg1h_h,
        const int* __restrict__ edge_src,
        const int* __restrict__ row_start,
        float* __restrict__ out, int N) {
    int wave = (blockIdx.x * blockDim.x + threadIdx.x) >> 6;
    if (wave >= N) return;
    int lane = threadIdx.x & 63;
    int eg = lane >> 2;
    int fq = lane & 3;
    int s = row_start[wave];
    int e = row_start[wave + 1];

    float acc[8] = {0.f,0.f,0.f,0.f,0.f,0.f,0.f,0.f};
    for (int i = s + eg; i < e; i += 16) {
        int src = edge_src[i];
        uint4 p = *(const uint4*)(agg1h_h + (size_t)src * HALF + fq * 8);
        acc[0] += bf_lo(p.x); acc[1] += bf_hi(p.x);
        acc[2] += bf_lo(p.y); acc[3] += bf_hi(p.y);
        acc[4] += bf_lo(p.z); acc[5] += bf_hi(p.z);
        acc[6] += bf_lo(p.w); acc[7] += bf_hi(p.w);
    }
    #pragma unroll
    for (int m = 4; m <= 32; m <<= 1) {
        #pragma unroll
        for (int k = 0; k < 8; ++k) acc[k] += __shfl_xor(acc[k], m, 64);
    }
    float inv = 1.0f / (float)((e - s) > 0 ? (e - s) : 1);
    #pragma unroll
    for (int k = 0; k < 8; ++k) acc[k] *= inv;

    if (eg == 0) {            // cols 192+32H..
        float* orow = out + (size_t)wave * 256;
        vfloat4 v0 = {acc[0], acc[1], acc[2], acc[3]};
        vfloat4 v1 = {acc[4], acc[5], acc[6], acc[7]};
        __builtin_nontemporal_store(v0, (vfloat4*)(orow + 192 + H * HALF + fq * 8));
        __builtin_nontemporal_store(v1, (vfloat4*)(orow + 192 + H * HALF + fq * 8 + 4));
    }
}

extern "C" void kernel_launch(void* const* d_in, const int* in_sizes, int n_in,
                              void* d_out, int out_size, void* d_ws, size_t ws_size,
                              hipStream_t stream) {
    const float* feat     = (const float*)d_in[0];
    const int*   edge_src = (const int*)d_in[1];
    const int*   edge_dst = (const int*)d_in[2];
    float*       out      = (float*)d_out;

    int N = in_sizes[0] / FEAT;
    int E = in_sizes[1];

    // ws layout: fbh [2][N][32] ushort, agg1h [2][N][32] ushort, row_start [N+1] int
    unsigned short* fbh   = (unsigned short*)d_ws;
    unsigned short* agg1h = fbh + (size_t)2 * N * HALF;
    int* row_start        = (int*)(agg1h + (size_t)2 * N * HALF);

    int prep_threads = N * 8;               // covers N+1 too
    prep<<<(prep_threads + 255) / 256, 256, 0, stream>>>(feat, edge_dst, fbh, row_start, N, E);

    int blocks = (N + 3) / 4;               // 4 waves (nodes) per block
    hop1_half<0><<<blocks, 256, 0, stream>>>(feat, fbh,               edge_src, row_start, out, agg1h,               N);
    hop1_half<1><<<blocks, 256, 0, stream>>>(feat, fbh + (size_t)N*HALF, edge_src, row_start, out, agg1h + (size_t)N*HALF, N);
    hop2_half<0><<<blocks, 256, 0, stream>>>(agg1h,               edge_src, row_start, out, N);
    hop2_half<1><<<blocks, 256, 0, stream>>>(agg1h + (size_t)N*HALF, edge_src, row_start, out, N);
}

// Round 6
// 60.510 us; speedup vs baseline: 1.6471x; 1.6471x over previous
//
#include <hip/hip_runtime.h>

#define FEAT 64

typedef float vfloat4 __attribute__((ext_vector_type(4)));

static __device__ __forceinline__ unsigned short f2bf(float f) {
    unsigned u = __float_as_uint(f);
    unsigned r = (u + 0x7FFF + ((u >> 16) & 1)) >> 16;   // RNE
    return (unsigned short)r;
}
static __device__ __forceinline__ float bf_lo(unsigned u) { return __uint_as_float(u << 16); }
static __device__ __forceinline__ float bf_hi(unsigned u) { return __uint_as_float(u & 0xffff0000u); }

// Fused prep: feat -> bf16 table, feat -> out[:,0:64] (f32, NT), CSR rowptr.
// One thread per 8 floats.
__global__ void prep(const float* __restrict__ feat,
                     const int* __restrict__ edge_dst,
                     unsigned short* __restrict__ fb16,
                     int* __restrict__ row_start,
                     float* __restrict__ out, int N, int E) {
    int t = blockIdx.x * blockDim.x + threadIdx.x;
    int total = N * 8;
    if (t < total) {
        int n = t >> 3, q = t & 7;
        const float* srcp = feat + (size_t)n * FEAT + q * 8;
        vfloat4 a = __builtin_nontemporal_load((const vfloat4*)srcp);
        vfloat4 b = __builtin_nontemporal_load((const vfloat4*)(srcp + 4));
        uint4 o;
        o.x = (unsigned)f2bf(a.x) | ((unsigned)f2bf(a.y) << 16);
        o.y = (unsigned)f2bf(a.z) | ((unsigned)f2bf(a.w) << 16);
        o.z = (unsigned)f2bf(b.x) | ((unsigned)f2bf(b.y) << 16);
        o.w = (unsigned)f2bf(b.z) | ((unsigned)f2bf(b.w) << 16);
        *(uint4*)(fb16 + (size_t)n * FEAT + q * 8) = o;           // gather table: cacheable
        float* orow = out + (size_t)n * 256 + q * 8;
        __builtin_nontemporal_store(a, (vfloat4*)orow);           // out cols 0:64
        __builtin_nontemporal_store(b, (vfloat4*)(orow + 4));
    }
    if (t <= N) {
        int lo = 0, hi = E;
        while (lo < hi) { int mid = (lo + hi) >> 1; if (edge_dst[mid] < t) lo = mid + 1; else hi = mid; }
        row_start[t] = lo;
    }
}

// Persistent-wave gather hop. eg = lane>>3 (8 edges in flight, 16 with unroll),
// fq = lane&7 (16B chunk = 8 bf16 of the full 64-dim row).
// IS_HOP2==0: table=fb16; writes out[n,64:128], out[n,128:192] (agg1 dup) f32 NT,
//             and agg1 bf16 -> agg1b (cacheable, hop2's table).
// IS_HOP2==1: table=agg1b; writes out[n,192:256] f32 NT.
template<int IS_HOP2>
__global__ void __launch_bounds__(256) hop(
        const unsigned short* __restrict__ table,
        const int* __restrict__ edge_src,
        const int* __restrict__ row_start,
        float* __restrict__ out,
        unsigned short* __restrict__ agg1b,
        int N, int nwaves) {
    int wid = (blockIdx.x * blockDim.x + threadIdx.x) >> 6;
    int lane = threadIdx.x & 63;
    int eg = lane >> 3;
    int fq = lane & 7;

    for (int n = wid; n < N; n += nwaves) {
        int s = row_start[n];
        int e = row_start[n + 1];
        float acc[8] = {0.f,0.f,0.f,0.f,0.f,0.f,0.f,0.f};

        int i = s + eg;
        // pipelined: two 8-edge batches in flight
        for (; i + 8 < e; i += 16) {
            int s0 = edge_src[i];
            int s1 = edge_src[i + 8];
            uint4 p0 = *(const uint4*)(table + (size_t)s0 * FEAT + fq * 8);
            uint4 p1 = *(const uint4*)(table + (size_t)s1 * FEAT + fq * 8);
            acc[0] += bf_lo(p0.x); acc[1] += bf_hi(p0.x);
            acc[2] += bf_lo(p0.y); acc[3] += bf_hi(p0.y);
            acc[4] += bf_lo(p0.z); acc[5] += bf_hi(p0.z);
            acc[6] += bf_lo(p0.w); acc[7] += bf_hi(p0.w);
            acc[0] += bf_lo(p1.x); acc[1] += bf_hi(p1.x);
            acc[2] += bf_lo(p1.y); acc[3] += bf_hi(p1.y);
            acc[4] += bf_lo(p1.z); acc[5] += bf_hi(p1.z);
            acc[6] += bf_lo(p1.w); acc[7] += bf_hi(p1.w);
        }
        if (i < e) {
            int s0 = edge_src[i];
            uint4 p0 = *(const uint4*)(table + (size_t)s0 * FEAT + fq * 8);
            acc[0] += bf_lo(p0.x); acc[1] += bf_hi(p0.x);
            acc[2] += bf_lo(p0.y); acc[3] += bf_hi(p0.y);
            acc[4] += bf_lo(p0.z); acc[5] += bf_hi(p0.z);
            acc[6] += bf_lo(p0.w); acc[7] += bf_hi(p0.w);
        }

        #pragma unroll
        for (int m = 8; m <= 32; m <<= 1) {
            #pragma unroll
            for (int k = 0; k < 8; ++k) acc[k] += __shfl_xor(acc[k], m, 64);
        }
        float inv = 1.0f / (float)((e - s) > 0 ? (e - s) : 1);
        #pragma unroll
        for (int k = 0; k < 8; ++k) acc[k] *= inv;

        float* orow = out + (size_t)n * 256;
        vfloat4 v0 = {acc[0], acc[1], acc[2], acc[3]};
        vfloat4 v1 = {acc[4], acc[5], acc[6], acc[7]};
        if (IS_HOP2) {
            if (eg == 0) {
                __builtin_nontemporal_store(v0, (vfloat4*)(orow + 192 + fq * 8));
                __builtin_nontemporal_store(v1, (vfloat4*)(orow + 192 + fq * 8 + 4));
            }
        } else {
            if (eg == 0) {            // cols 64:128 = agg1
                __builtin_nontemporal_store(v0, (vfloat4*)(orow + 64 + fq * 8));
                __builtin_nontemporal_store(v1, (vfloat4*)(orow + 64 + fq * 8 + 4));
            } else if (eg == 1) {     // cols 128:192 = agg1 dup (== agg2[:,0:64])
                __builtin_nontemporal_store(v0, (vfloat4*)(orow + 128 + fq * 8));
                __builtin_nontemporal_store(v1, (vfloat4*)(orow + 128 + fq * 8 + 4));
            } else if (eg == 2) {     // agg1 bf16 -> hop2's gather table (cacheable)
                uint4 pk;
                pk.x = (unsigned)f2bf(acc[0]) | ((unsigned)f2bf(acc[1]) << 16);
                pk.y = (unsigned)f2bf(acc[2]) | ((unsigned)f2bf(acc[3]) << 16);
                pk.z = (unsigned)f2bf(acc[4]) | ((unsigned)f2bf(acc[5]) << 16);
                pk.w = (unsigned)f2bf(acc[6]) | ((unsigned)f2bf(acc[7]) << 16);
                *(uint4*)(agg1b + (size_t)n * FEAT + fq * 8) = pk;
            }
        }
    }
}

extern "C" void kernel_launch(void* const* d_in, const int* in_sizes, int n_in,
                              void* d_out, int out_size, void* d_ws, size_t ws_size,
                              hipStream_t stream) {
    const float* feat     = (const float*)d_in[0];
    const int*   edge_src = (const int*)d_in[1];
    const int*   edge_dst = (const int*)d_in[2];
    float*       out      = (float*)d_out;

    int N = in_sizes[0] / FEAT;
    int E = in_sizes[1];

    // ws: fb16 [N*64] ushort, agg1b [N*64] ushort, row_start [N+1] int
    unsigned short* fb16  = (unsigned short*)d_ws;
    unsigned short* agg1b = fb16 + (size_t)N * FEAT;
    int* row_start        = (int*)(agg1b + (size_t)N * FEAT);

    prep<<<(N * 8 + 255) / 256, 256, 0, stream>>>(feat, edge_dst, fb16, row_start, out, N, E);

    // persistent waves: 2048 blocks x 4 waves = 8192 waves = 32 waves/CU
    const int BLOCKS = 2048;
    const int NWAVES = BLOCKS * 4;
    hop<0><<<BLOCKS, 256, 0, stream>>>(fb16,  edge_src, row_start, out, agg1b, N, NWAVES);
    hop<1><<<BLOCKS, 256, 0, stream>>>(agg1b, edge_src, row_start, out, agg1b, N, NWAVES);
}

// Round 7
// 55.813 us; speedup vs baseline: 1.7857x; 1.0842x over previous
//
#include <hip/hip_runtime.h>

#define FEAT 64

typedef float vfloat4 __attribute__((ext_vector_type(4)));
typedef float vfloat2 __attribute__((ext_vector_type(2)));

// Decode 8 fp8(e4m3) values held in a uint2 into acc[0..7] (HW cvt, 2 vals/op).
#define ACC8(P)                                                            \
    {                                                                      \
        vfloat2 f0 = __builtin_amdgcn_cvt_pk_f32_fp8((int)(P).x, false);   \
        vfloat2 f1 = __builtin_amdgcn_cvt_pk_f32_fp8((int)(P).x, true);    \
        vfloat2 f2 = __builtin_amdgcn_cvt_pk_f32_fp8((int)(P).y, false);   \
        vfloat2 f3 = __builtin_amdgcn_cvt_pk_f32_fp8((int)(P).y, true);    \
        acc[0] += f0.x; acc[1] += f0.y; acc[2] += f1.x; acc[3] += f1.y;    \
        acc[4] += f2.x; acc[5] += f2.y; acc[6] += f3.x; acc[7] += f3.y;    \
    }

// Fused prep: feat -> fp8 table, feat -> out[:,0:64] f32 (NT), CSR rowptr.
// One thread per 8 floats.
__global__ void prep(const float* __restrict__ feat,
                     const int* __restrict__ edge_dst,
                     unsigned char* __restrict__ ftab,    // [N][64] fp8
                     int* __restrict__ row_start,
                     float* __restrict__ out, int N, int E) {
    int t = blockIdx.x * blockDim.x + threadIdx.x;
    int total = N * 8;
    if (t < total) {
        int n = t >> 3, q = t & 7;
        const float* srcp = feat + (size_t)n * FEAT + q * 8;
        vfloat4 a = __builtin_nontemporal_load((const vfloat4*)srcp);
        vfloat4 b = __builtin_nontemporal_load((const vfloat4*)(srcp + 4));
        int w0 = __builtin_amdgcn_cvt_pk_fp8_f32(a.x, a.y, 0, false);
        w0     = __builtin_amdgcn_cvt_pk_fp8_f32(a.z, a.w, w0, true);
        int w1 = __builtin_amdgcn_cvt_pk_fp8_f32(b.x, b.y, 0, false);
        w1     = __builtin_amdgcn_cvt_pk_fp8_f32(b.z, b.w, w1, true);
        uint2 o; o.x = (unsigned)w0; o.y = (unsigned)w1;
        *(uint2*)(ftab + (size_t)n * FEAT + q * 8) = o;           // gather table: cacheable
        float* orow = out + (size_t)n * 256 + q * 8;
        __builtin_nontemporal_store(a, (vfloat4*)orow);           // out cols 0:64 (exact f32)
        __builtin_nontemporal_store(b, (vfloat4*)(orow + 4));
    }
    if (t <= N) {
        int lo = 0, hi = E;
        while (lo < hi) { int mid = (lo + hi) >> 1; if (edge_dst[mid] < t) lo = mid + 1; else hi = mid; }
        row_start[t] = lo;
    }
}

// Persistent-wave gather hop over an fp8 table.
// eg = lane>>3 (8 edges in flight, 16 pipelined), fq = lane&7 (8B = 8 fp8 dims).
// IS_HOP2==0: table=ftab; writes out[n,64:128] + out[n,128:192] (agg1 dup) f32 NT,
//             and agg1 fp8 -> agg1t (hop2's gather table).
// IS_HOP2==1: table=agg1t; writes out[n,192:256] f32 NT.
template<int IS_HOP2>
__global__ void __launch_bounds__(256) hop(
        const unsigned char* __restrict__ table,
        const int* __restrict__ edge_src,
        const int* __restrict__ row_start,
        float* __restrict__ out,
        unsigned char* __restrict__ agg1t,
        int N, int nwaves) {
    int wid = (blockIdx.x * blockDim.x + threadIdx.x) >> 6;
    int lane = threadIdx.x & 63;
    int eg = lane >> 3;
    int fq = lane & 7;

    for (int n = wid; n < N; n += nwaves) {
        int s = row_start[n];
        int e = row_start[n + 1];
        float acc[8] = {0.f,0.f,0.f,0.f,0.f,0.f,0.f,0.f};

        int i = s + eg;
        for (; i + 8 < e; i += 16) {            // two 8-edge batches in flight
            int s0 = edge_src[i];
            int s1 = edge_src[i + 8];
            uint2 p0 = *(const uint2*)(table + (size_t)s0 * FEAT + fq * 8);
            uint2 p1 = *(const uint2*)(table + (size_t)s1 * FEAT + fq * 8);
            ACC8(p0);
            ACC8(p1);
        }
        if (i < e) {
            int s0 = edge_src[i];
            uint2 p0 = *(const uint2*)(table + (size_t)s0 * FEAT + fq * 8);
            ACC8(p0);
        }

        #pragma unroll
        for (int m = 8; m <= 32; m <<= 1) {
            #pragma unroll
            for (int k = 0; k < 8; ++k) acc[k] += __shfl_xor(acc[k], m, 64);
        }
        float inv = 1.0f / (float)((e - s) > 0 ? (e - s) : 1);
        #pragma unroll
        for (int k = 0; k < 8; ++k) acc[k] *= inv;

        float* orow = out + (size_t)n * 256;
        vfloat4 v0 = {acc[0], acc[1], acc[2], acc[3]};
        vfloat4 v1 = {acc[4], acc[5], acc[6], acc[7]};
        if (IS_HOP2) {
            if (eg == 0) {
                __builtin_nontemporal_store(v0, (vfloat4*)(orow + 192 + fq * 8));
                __builtin_nontemporal_store(v1, (vfloat4*)(orow + 192 + fq * 8 + 4));
            }
        } else {
            if (eg == 0) {            // cols 64:128 = agg1 (f32)
                __builtin_nontemporal_store(v0, (vfloat4*)(orow + 64 + fq * 8));
                __builtin_nontemporal_store(v1, (vfloat4*)(orow + 64 + fq * 8 + 4));
            } else if (eg == 1) {     // cols 128:192 = agg1 dup (== agg2[:,0:64])
                __builtin_nontemporal_store(v0, (vfloat4*)(orow + 128 + fq * 8));
                __builtin_nontemporal_store(v1, (vfloat4*)(orow + 128 + fq * 8 + 4));
            } else if (eg == 2) {     // agg1 fp8 -> hop2's gather table
                int w0 = __builtin_amdgcn_cvt_pk_fp8_f32(acc[0], acc[1], 0, false);
                w0     = __builtin_amdgcn_cvt_pk_fp8_f32(acc[2], acc[3], w0, true);
                int w1 = __builtin_amdgcn_cvt_pk_fp8_f32(acc[4], acc[5], 0, false);
                w1     = __builtin_amdgcn_cvt_pk_fp8_f32(acc[6], acc[7], w1, true);
                uint2 pk; pk.x = (unsigned)w0; pk.y = (unsigned)w1;
                *(uint2*)(agg1t + (size_t)n * FEAT + fq * 8) = pk;
            }
        }
    }
}

extern "C" void kernel_launch(void* const* d_in, const int* in_sizes, int n_in,
                              void* d_out, int out_size, void* d_ws, size_t ws_size,
                              hipStream_t stream) {
    const float* feat     = (const float*)d_in[0];
    const int*   edge_src = (const int*)d_in[1];
    const int*   edge_dst = (const int*)d_in[2];
    float*       out      = (float*)d_out;

    int N = in_sizes[0] / FEAT;
    int E = in_sizes[1];

    // ws: ftab [N*64] fp8, agg1t [N*64] fp8, row_start [N+1] int
    unsigned char* ftab  = (unsigned char*)d_ws;
    unsigned char* agg1t = ftab + (size_t)N * FEAT;
    int* row_start       = (int*)(agg1t + (size_t)N * FEAT);

    prep<<<(N * 8 + 255) / 256, 256, 0, stream>>>(feat, edge_dst, ftab, row_start, out, N, E);

    // persistent waves: 2048 blocks x 4 waves = 8192 waves = 32 waves/CU
    const int BLOCKS = 2048;
    const int NWAVES = BLOCKS * 4;
    hop<0><<<BLOCKS, 256, 0, stream>>>(ftab,  edge_src, row_start, out, agg1t, N, NWAVES);
    hop<1><<<BLOCKS, 256, 0, stream>>>(agg1t, edge_src, row_start, out, agg1t, N, NWAVES);
}